// Round 8
// baseline (482.425 us; speedup 1.0000x reference)
//
#include <hip/hip_runtime.h>
#include <math.h>

// Problem constants (from reference)
#define NM 20301          // mesh points (201*202/2)
#define TT 4096           // time steps
#define NCC 256           // chunks over T (one per states-block)
#define CH2 16            // steps per chunk = TT/NCC
#define NBLK 80           // ceil(NM/256)  (for the 256-thread n-kernels)
#define NTH 1024          // threads per states block (16 waves, 1 block/CU)
#define KPT 20            // n's per thread: 1024*20 = 20480 >= 20301
#define LOG2E_K 1442.69504f   // 1000 * log2(e)  (temp = 0.001)
// Saturation cutoff in log2-scaled units: |w|>=26 <=> |z|>=18.0 natural.
#define WNEAR 26.0f

// Fused soft-relay step (slow path): one rcp instead of two.
__device__ __forceinline__ void relay_step(float ka, float kb, float ku,
                                           float& aa, float& bb) {
    float z1 = fminf(ka - ku, 63.f);
    float z2 = fminf(ku - kb, 63.f);
    float e1 = __builtin_amdgcn_exp2f(z1);
    float e2 = __builtin_amdgcn_exp2f(z2);
    float p1 = 1.f + e1, p2 = 1.f + e2;
    float r  = __builtin_amdgcn_rcpf(p1 * p2);
    aa = (e2 - e1) * r;
    bb = (e1 * e2) * r;
}

__device__ __forceinline__ float wave_reduce_sum(float w) {
    #pragma unroll
    for (int off = 32; off > 0; off >>= 1)
        w += __shfl_down(w, off, 64);
    return w;
}

// ---------------- density MLP: [N,2] -> 16 -> 16 -> 16 -> 1 ----------------
__global__ __launch_bounds__(256) void density_kernel(
    const float* __restrict__ alpha, const float* __restrict__ beta,
    const float* __restrict__ w1, const float* __restrict__ b1,
    const float* __restrict__ w2, const float* __restrict__ b2,
    const float* __restrict__ w3, const float* __restrict__ b3,
    const float* __restrict__ w4, const float* __restrict__ b4,
    float* __restrict__ density_out, float* __restrict__ densum_parts)
{
    int n = blockIdx.x * 256 + threadIdx.x;
    bool valid = n < NM;
    int nn = valid ? n : NM - 1;
    float a = alpha[nn], b = beta[nn];

    float h1[16], h2[16], h3[16];
    #pragma unroll
    for (int j = 0; j < 16; j++) {
        float v = fmaf(a, w1[j], fmaf(b, w1[16 + j], b1[j]));
        h1[j] = fmaxf(v, 0.f);
    }
    #pragma unroll
    for (int j = 0; j < 16; j++) {
        float v = b2[j];
        #pragma unroll
        for (int k = 0; k < 16; k++) v = fmaf(h1[k], w2[k * 16 + j], v);
        h2[j] = fmaxf(v, 0.f);
    }
    #pragma unroll
    for (int j = 0; j < 16; j++) {
        float v = b3[j];
        #pragma unroll
        for (int k = 0; k < 16; k++) v = fmaf(h2[k], w3[k * 16 + j], v);
        h3[j] = fmaxf(v, 0.f);
    }
    float v = b4[0];
    #pragma unroll
    for (int k = 0; k < 16; k++) v = fmaf(h3[k], w4[k], v);
    float d = 1.f / (1.f + __expf(-v));

    if (valid) density_out[n] = d;
    float wsum = wave_reduce_sum(valid ? d : 0.f);
    __shared__ float ws_[4];
    if ((threadIdx.x & 63) == 0) ws_[threadIdx.x >> 6] = wsum;
    __syncthreads();
    if (threadIdx.x == 0)
        densum_parts[blockIdx.x] = ws_[0] + ws_[1] + ws_[2] + ws_[3];
}

// ---- pass 1: per-(n,chunk) affine composite over CH2=16 steps -------------
__global__ __launch_bounds__(256) void chunk_compose_kernel(
    const float* __restrict__ x, const float* __restrict__ alpha,
    const float* __restrict__ beta,
    float* __restrict__ Abuf, float* __restrict__ Bbuf)
{
    __shared__ float xs[CH2];
    int c = blockIdx.y;
    if (threadIdx.x < CH2) xs[threadIdx.x] = x[c * CH2 + threadIdx.x] * LOG2E_K;
    __syncthreads();

    int n = blockIdx.x * 256 + threadIdx.x;
    int nn = (n < NM) ? n : NM - 1;
    float ka = alpha[nn] * LOG2E_K;
    float kb = beta[nn] * LOG2E_K;

    float A = 0.f, B = 1.f;
    #pragma unroll
    for (int j = 0; j < CH2; j++) {
        float ku = xs[j];
        float w1 = ka - ku, w2 = ku - kb;
        bool nearb = fminf(fabsf(w1), fabsf(w2)) < WNEAR;
        if (__any(nearb)) {                  // wave-uniform branch
            float aa, bb;
            relay_step(ka, kb, ku, aa, bb);
            A = fmaf(bb, A, aa);
            B *= bb;
        } else {
            bool swu = w1 < 0.f, swd = w2 < 0.f;
            A = swu ? 1.f : (swd ? -1.f : A);
            B = (swu || swd) ? 0.f : B;
        }
    }
    if (n < NM) { Abuf[(size_t)c * NM + n] = A; Bbuf[(size_t)c * NM + n] = B; }
}

// ---- pass 2: sequential scan over the 256 chunk boundaries ----------------
__global__ __launch_bounds__(256) void chunk_scan_kernel(
    const float* __restrict__ init_raw,
    const float* __restrict__ Abuf, const float* __restrict__ Bbuf,
    float* __restrict__ sstart)
{
    int n = blockIdx.x * 256 + threadIdx.x;
    if (n >= NM) return;
    float s = tanhf(init_raw[n]);
    #pragma unroll 4
    for (int c = 0; c < NCC; c++) {
        sstart[(size_t)c * NM + n] = s;             // state entering chunk c
        s = fmaf(Bbuf[(size_t)c * NM + n], s, Abuf[(size_t)c * NM + n]);
    }
}

// ---- pass 3: ROW-STREAMING states. 256 blocks (1/CU) x 1024 threads; -----
// block b owns t in [16b,16b+16) and ALL n (state in registers, KPT=20/thr).
// Per t the block writes one full 81-KB row CONTIGUOUSLY; rows advance
// sequentially -> 256 long sequential write streams (fill-like DRAM page
// locality), vs the old 5120 interleaved 256-B column streams.
// Reduction is per-wave only (shfl + 1 dword store) - no barriers, no
// vmcnt drains in the hot loop.
__global__ __launch_bounds__(NTH) void states_kernel(
    const float* __restrict__ x, const float* __restrict__ alpha,
    const float* __restrict__ beta, const float* __restrict__ density,
    const float* __restrict__ sstart,
    float* __restrict__ states, float* __restrict__ wpart)
{
    __shared__ float xsh[CH2];
    int b = blockIdx.x;                // t-chunk index (== scan chunk c)
    int tid = threadIdx.x;
    if (tid < CH2) xsh[tid] = x[b * CH2 + tid] * LOG2E_K;

    float s_reg[KPT], d_reg[KPT], ka[KPT], kb[KPT];
    #pragma unroll
    for (int k = 0; k < KPT; k++) {
        int n = tid + NTH * k;
        bool v = n < NM;
        int nn = v ? n : NM - 1;
        ka[k] = alpha[nn] * LOG2E_K;
        kb[k] = beta[nn] * LOG2E_K;
        d_reg[k] = v ? density[n] : 0.f;
        s_reg[k] = sstart[(size_t)b * NM + nn];
    }
    __syncthreads();                   // xsh ready; no barriers after this

    int wv = tid >> 6;                 // 16 waves
    for (int t = 0; t < CH2; t++) {
        float u = xsh[t];
        float* __restrict__ row = states + (size_t)(b * CH2 + t) * NM;
        float acc = 0.f;
        #pragma unroll
        for (int k = 0; k < KPT; k++) {
            int n = tid + NTH * k;
            float w1 = ka[k] - u, w2 = u - kb[k];
            float s = s_reg[k];
            bool nearb = fminf(fabsf(w1), fabsf(w2)) < WNEAR;
            if (__any(nearb)) {        // wave-uniform branch
                float aa, bb;
                relay_step(ka[k], kb[k], u, aa, bb);
                s = fmaf(bb, s, aa);
            } else {
                s = (w1 < 0.f) ? 1.f : ((w2 < 0.f) ? -1.f : s);
            }
            s_reg[k] = s;
            if (n < NM) row[n] = s;    // coalesced, row fills contiguously
            acc = fmaf(d_reg[k], s, acc);
        }
        // per-wave reduction only: no cross-wave sync needed
        acc = wave_reduce_sum(acc);
        if ((tid & 63) == 0)
            wpart[(size_t)(b * 16 + wv) * CH2 + t] = acc;
    }
}

// ---- pass 4: fold 16 wave-partials per t + 80 densum parts ----------------
__global__ __launch_bounds__(256) void finalize_kernel(
    const float* __restrict__ x, const float* __restrict__ wpart,
    const float* __restrict__ densum_parts,
    const float* __restrict__ msr, const float* __restrict__ mor,
    const float* __restrict__ hsr, float* __restrict__ out)
{
    int t = blockIdx.x * 256 + threadIdx.x;
    if (t >= TT) return;
    int b = t >> 4, tl = t & 15;
    float acc = 0.f;
    #pragma unroll
    for (int w = 0; w < 16; w++)
        acc += wpart[(size_t)(b * 16 + w) * CH2 + tl];
    float dsum = 0.f;
    for (int bx = 0; bx < NBLK; bx++)
        dsum += densum_parts[bx];               // uniform -> scalar loads
    float sig_ms = 1.f / (1.f + __expf(-msr[0]));
    float sig_mo = 1.f / (1.f + __expf(-mor[0]));
    float sig_hs = 1.f / (1.f + __expf(-hsr[0]));
    float m_scale  = 10.f * sig_ms;
    float m_offset = fmaf(20.f, sig_mo, -10.f);
    float h_scale  = 10.f * sig_hs;
    float m = acc / dsum;
    out[t] = fmaf(m_scale, m, m_offset) + h_scale * x[t];
}

extern "C" void kernel_launch(void* const* d_in, const int* in_sizes, int n_in,
                              void* d_out, int out_size, void* d_ws, size_t ws_size,
                              hipStream_t stream)
{
    // setup_inputs() dict order:
    const float* x    = (const float*)d_in[0];   // [4096]
    const float* alpha= (const float*)d_in[1];   // [20301]
    const float* beta = (const float*)d_in[2];   // [20301]
    const float* init = (const float*)d_in[3];   // [20301]
    const float* msr  = (const float*)d_in[4];   // [1]
    const float* mor  = (const float*)d_in[5];   // [1]
    const float* hsr  = (const float*)d_in[6];   // [1]
    const float* w1   = (const float*)d_in[7];   // [2,16]
    const float* b1   = (const float*)d_in[8];   // [16]
    const float* w2   = (const float*)d_in[9];   // [16,16]
    const float* b2   = (const float*)d_in[10];  // [16]
    const float* w3   = (const float*)d_in[11];  // [16,16]
    const float* b3   = (const float*)d_in[12];  // [16]
    const float* w4   = (const float*)d_in[13];  // [16,1]
    const float* b4   = (const float*)d_in[14];  // [1]

    float* out     = (float*)d_out;          // [TT]
    float* density = out + TT;               // [NM]
    float* states  = density + NM;           // [TT*NM]

    // ws layout: densum_parts[80] | pad | sstart[NCC*NM] | wpart[256*16*16]
    float* densum_parts = (float*)d_ws;
    float* sstart       = densum_parts + 128;
    float* wpart        = sstart + (size_t)NCC * NM;

    // (A,B) chunk composites (2 x 20.8 MB) stashed in the states region of
    // d_out; fully consumed by chunk_scan before states overwrites.
    float* Abuf = states;
    float* Bbuf = states + (size_t)NCC * NM;

    density_kernel<<<dim3(NBLK), dim3(256), 0, stream>>>(
        alpha, beta, w1, b1, w2, b2, w3, b3, w4, b4, density, densum_parts);

    chunk_compose_kernel<<<dim3(NBLK, NCC), dim3(256), 0, stream>>>(
        x, alpha, beta, Abuf, Bbuf);

    chunk_scan_kernel<<<dim3(NBLK), dim3(256), 0, stream>>>(
        init, Abuf, Bbuf, sstart);

    states_kernel<<<dim3(NCC), dim3(NTH), 0, stream>>>(
        x, alpha, beta, density, sstart, states, wpart);

    finalize_kernel<<<dim3(TT / 256), dim3(256), 0, stream>>>(
        x, wpart, densum_parts, msr, mor, hsr, out);
}